// Round 5
// baseline (133.183 us; speedup 1.0000x reference)
//
#include <hip/hip_runtime.h>
#include <hip/hip_bf16.h>

#define D 128          // D_IN == D_OUT
#define K2 256         // 2*D (concat width)
#define NT 64          // nodes per block (16 per wave)
#define NTHREADS 256
#define AGG_LD 264     // bf16 elems per aggB row -> 528B stride

typedef __attribute__((ext_vector_type(8))) short bf16x8;  // MFMA A/B frag
typedef __attribute__((ext_vector_type(4))) float f32x4;   // MFMA C/D frag

static __device__ __forceinline__ unsigned short f2bf(float f) {
    __hip_bfloat16 h = __float2bfloat16(f);   // RNE
    return *reinterpret_cast<unsigned short*>(&h);
}

// -------- Kernel A: convert x_feat AND W fp32 -> bf16 tables in d_ws --------
__global__ __launch_bounds__(256)
void convert_all(const float* __restrict__ x, const float* __restrict__ W,
                 unsigned int* __restrict__ xb2, unsigned int* __restrict__ wb2,
                 long n4x, long n4w)
{
    long i = (long)blockIdx.x * blockDim.x + threadIdx.x;
    const long stride = (long)gridDim.x * blockDim.x;
    const long tot = n4x + n4w;
    for (; i < tot; i += stride) {
        const float4 v = (i < n4x) ? reinterpret_cast<const float4*>(x)[i]
                                   : reinterpret_cast<const float4*>(W)[i - n4x];
        const unsigned int lo = (unsigned int)f2bf(v.x) | ((unsigned int)f2bf(v.y) << 16);
        const unsigned int hi = (unsigned int)f2bf(v.z) | ((unsigned int)f2bf(v.w) << 16);
        const uint2 p = make_uint2(lo, hi);
        if (i < n4x) reinterpret_cast<uint2*>(xb2)[i] = p;
        else         reinterpret_cast<uint2*>(wb2)[i - n4x] = p;
    }
}

// ---- Kernel B: barrier-free gather + mean + concat + per-wave MFMA GEMM ----
// Each wave owns 16 nodes end-to-end: gathers them into its private aggB rows,
// then computes their 16x128 output tile. No __syncthreads anywhere.
__global__ __launch_bounds__(NTHREADS, 4)
void sage_nobar(const unsigned short* __restrict__ xb,
                const unsigned short* __restrict__ wb,
                const int* __restrict__ rp,
                const int* __restrict__ ci,
                const float* __restrict__ lb,
                const float* __restrict__ bb,
                float* __restrict__ y,
                int n_out)
{
    __shared__ unsigned short aggB[NT][AGG_LD];  // bf16 [self(128) | mean(128)]
    __shared__ int cils[NT * 16];                // wave-private 256-entry slices

    const int tid   = threadIdx.x;
    const int wave  = tid >> 6;
    const int lane  = tid & 63;
    const int node0 = blockIdx.x * NT;
    const int wbase = node0 + wave * 16;
    const int nw    = min(16, n_out - wbase);    // nodes this wave owns
    if (nw <= 0) return;

    // ---- per-wave row_ptr slice via shuffle (no LDS, no barrier) ----
    const int rv    = rp[wbase + min(lane, nw)];
    const int ebase = __shfl(rv, 0);
    const int ecnt  = __shfl(rv, nw) - ebase;
    const bool staged = (ecnt <= 256);

    int* const mycil = &cils[wave * 256];
    if (staged) {
        if (nw == 16 && ecnt == 256 && ((ebase & 3) == 0)) {
            // fast path: one int4 per lane
            const int4 iv = *reinterpret_cast<const int4*>(&ci[ebase + lane * 4]);
            *reinterpret_cast<int4*>(&mycil[lane * 4]) = iv;
        } else {
            for (int i = lane; i < ecnt; i += 64) mycil[i] = ci[ebase + i];
        }
    }
    // wave-internal ds_write -> ds_read ordering handled by compiler lgkmcnt

    // ---- Phase 1: gather (2 nodes/iter -> 32 independent 4B/lane loads) ----
    for (int t = 0; t < nw; t += 2) {
        const int nn0  = wave * 16 + t;
        const bool has1 = (t + 1 < nw);
        const int nn1  = nn0 + 1;

        const int r0 = __shfl(rv, t);
        const int r1 = __shfl(rv, t + 1);
        const int r2 = has1 ? __shfl(rv, t + 2) : r1;
        const int s0 = r0 - ebase, d0 = r1 - r0;
        const int s1 = r1 - ebase, d1 = r2 - r1;

        const unsigned int self0 = *reinterpret_cast<const unsigned int*>(
            &xb[(size_t)(wbase + t) * D + lane * 2]);
        unsigned int self1 = 0;
        if (has1) self1 = *reinterpret_cast<const unsigned int*>(
            &xb[(size_t)(wbase + t + 1) * D + lane * 2]);

        float a0x = 0.f, a0y = 0.f, a1x = 0.f, a1y = 0.f;
        if (staged && d0 == 16 && d1 == 16 && has1) {
            int idx0[16], idx1[16];
            #pragma unroll
            for (int u = 0; u < 16; ++u) { idx0[u] = mycil[s0 + u]; idx1[u] = mycil[s1 + u]; }
            #pragma unroll
            for (int u = 0; u < 16; ++u) {
                const unsigned int v0 = *reinterpret_cast<const unsigned int*>(
                    &xb[(size_t)idx0[u] * D + lane * 2]);
                const unsigned int v1 = *reinterpret_cast<const unsigned int*>(
                    &xb[(size_t)idx1[u] * D + lane * 2]);
                a0x += __uint_as_float(v0 << 16);
                a0y += __uint_as_float(v0 & 0xffff0000u);
                a1x += __uint_as_float(v1 << 16);
                a1y += __uint_as_float(v1 & 0xffff0000u);
            }
        } else {
            for (int u = 0; u < d0; ++u) {
                const int c = staged ? mycil[s0 + u] : ci[ebase + s0 + u];
                const unsigned int v = *reinterpret_cast<const unsigned int*>(
                    &xb[(size_t)c * D + lane * 2]);
                a0x += __uint_as_float(v << 16);
                a0y += __uint_as_float(v & 0xffff0000u);
            }
            for (int u = 0; u < d1; ++u) {
                const int c = staged ? mycil[s1 + u] : ci[ebase + s1 + u];
                const unsigned int v = *reinterpret_cast<const unsigned int*>(
                    &xb[(size_t)c * D + lane * 2]);
                a1x += __uint_as_float(v << 16);
                a1y += __uint_as_float(v & 0xffff0000u);
            }
        }

        const float inv0 = 1.0f / (float)max(d0, 1);
        *reinterpret_cast<unsigned int*>(&aggB[nn0][lane * 2]) = self0;
        *reinterpret_cast<unsigned int*>(&aggB[nn0][D + lane * 2]) =
            (unsigned int)f2bf(a0x * inv0) | ((unsigned int)f2bf(a0y * inv0) << 16);
        if (has1) {
            const float inv1 = 1.0f / (float)max(d1, 1);
            *reinterpret_cast<unsigned int*>(&aggB[nn1][lane * 2]) = self1;
            *reinterpret_cast<unsigned int*>(&aggB[nn1][D + lane * 2]) =
                (unsigned int)f2bf(a1x * inv1) | ((unsigned int)f2bf(a1y * inv1) << 16);
        }
    }

    // ---- Phase 2: per-wave MFMA GEMM, M=16 x N=128, K=256; B from global ----
    const int n15 = lane & 15;
    const int g   = lane >> 4;

    f32x4 acc[8];
    #pragma unroll
    for (int f = 0; f < 8; ++f) acc[f] = (f32x4){0.f, 0.f, 0.f, 0.f};

    #pragma unroll
    for (int k0 = 0; k0 < K2; k0 += 32) {
        const bf16x8 a = *reinterpret_cast<const bf16x8*>(
            &aggB[wave * 16 + n15][k0 + g * 8]);   // own wave's rows only
        #pragma unroll
        for (int f = 0; f < 8; ++f) {
            const bf16x8 b = *reinterpret_cast<const bf16x8*>(
                &wb[(size_t)(f * 16 + n15) * K2 + k0 + g * 8]);  // L2-resident
            acc[f] = __builtin_amdgcn_mfma_f32_16x16x32_bf16(a, b, acc[f], 0, 0, 0);
        }
    }

    // ---- Epilogue: D layout col = lane&15, row = (lane>>4)*4 + reg ----
    const int mbase = wbase + g * 4;
    #pragma unroll
    for (int f = 0; f < 8; ++f) {
        const int col  = f * 16 + n15;
        const float bs = lb[col] + bb[col];
        #pragma unroll
        for (int r = 0; r < 4; ++r) {
            const int row = mbase + r;
            if (row < n_out)
                y[(size_t)row * D + col] = acc[f][r] + bs;
        }
    }
}

// --------- Fallback (fp32 gather, barriered) if ws too small ---------
#define AGG_LDF 264
__global__ __launch_bounds__(NTHREADS, 3)
void sage_fused3(const float* __restrict__ x,
                 const int* __restrict__ rp,
                 const int* __restrict__ ci,
                 const float* __restrict__ W,
                 const float* __restrict__ lb,
                 const float* __restrict__ bb,
                 float* __restrict__ y,
                 int n_out)
{
    __shared__ unsigned short aggB[NT][AGG_LDF];
    __shared__ unsigned short wtT[D][32];
    __shared__ int rpls[NT + 1];
    __shared__ int cilsF[NT * 16];

    const int tid   = threadIdx.x;
    const int wave  = tid >> 6;
    const int lane  = tid & 63;
    const int node0 = blockIdx.x * NT;
    const int nt_act = min(NT, n_out - node0);

    if (tid <= nt_act) rpls[tid] = rp[node0 + tid];
    __syncthreads();
    const int e_base = rpls[0];
    const int e_cnt  = rpls[nt_act] - e_base;
    const bool fits  = (e_cnt <= NT * 16);
    if (fits) {
        for (int i = tid; i < e_cnt; i += NTHREADS) cilsF[i] = ci[e_base + i];
    }
    __syncthreads();

    for (int t = 0; t < 16; ++t) {
        const int nn = wave * 16 + t;
        if (nn >= nt_act) break;
        const int node = node0 + nn;
        const float2 self =
            *reinterpret_cast<const float2*>(&x[(size_t)node * D + lane * 2]);
        const int s  = rpls[nn] - e_base;
        const int dg = rpls[nn + 1] - e_base - s;
        float ax = 0.f, ay = 0.f;
        for (int u = 0; u < dg; ++u) {
            const int c = fits ? cilsF[s + u] : ci[e_base + s + u];
            const float2 v = *reinterpret_cast<const float2*>(
                &x[(size_t)c * D + lane * 2]);
            ax += v.x; ay += v.y;
        }
        const float inv = 1.0f / (float)max(dg, 1);
        *reinterpret_cast<unsigned int*>(&aggB[nn][lane * 2]) =
            (unsigned int)f2bf(self.x) | ((unsigned int)f2bf(self.y) << 16);
        *reinterpret_cast<unsigned int*>(&aggB[nn][D + lane * 2]) =
            (unsigned int)f2bf(ax * inv) | ((unsigned int)f2bf(ay * inv) << 16);
    }

    const int n15 = lane & 15;
    const int g   = lane >> 4;
    f32x4 acc[8];
    #pragma unroll
    for (int f = 0; f < 8; ++f) acc[f] = (f32x4){0.f, 0.f, 0.f, 0.f};

    for (int k0 = 0; k0 < K2; k0 += 32) {
        #pragma unroll
        for (int j = 0; j < 4; ++j) {
            const int idx = j * 256 + tid;
            const int o   = idx >> 3;
            const int c   = idx & 7;
            const float4 w = *reinterpret_cast<const float4*>(
                &W[(size_t)o * K2 + k0 + c * 4]);
            const unsigned int lo = (unsigned int)f2bf(w.x) | ((unsigned int)f2bf(w.y) << 16);
            const unsigned int hi = (unsigned int)f2bf(w.z) | ((unsigned int)f2bf(w.w) << 16);
            *reinterpret_cast<uint2*>(&wtT[o][c * 4]) = make_uint2(lo, hi);
        }
        __syncthreads();
        const bf16x8 a = *reinterpret_cast<const bf16x8*>(
            &aggB[wave * 16 + n15][k0 + g * 8]);
        #pragma unroll
        for (int f = 0; f < 8; ++f) {
            const bf16x8 b = *reinterpret_cast<const bf16x8*>(&wtT[f * 16 + n15][g * 8]);
            acc[f] = __builtin_amdgcn_mfma_f32_16x16x32_bf16(a, b, acc[f], 0, 0, 0);
        }
        __syncthreads();
    }

    const int mbase = node0 + wave * 16 + g * 4;
    #pragma unroll
    for (int f = 0; f < 8; ++f) {
        const int col  = f * 16 + n15;
        const float bs = lb[col] + bb[col];
        #pragma unroll
        for (int r = 0; r < 4; ++r) {
            const int row = mbase + r;
            if (row < n_out)
                y[(size_t)row * D + col] = acc[f][r] + bs;
        }
    }
}

extern "C" void kernel_launch(void* const* d_in, const int* in_sizes, int n_in,
                              void* d_out, int out_size, void* d_ws, size_t ws_size,
                              hipStream_t stream)
{
    const float* x  = (const float*)d_in[0];
    const int*   rp = (const int*)d_in[1];
    const int*   ci = (const int*)d_in[2];
    // d_in[3] = sample_count (scalar) — degree comes from row_ptr
    const float* W  = (const float*)d_in[4];
    const float* lb = (const float*)d_in[5];
    const float* bb = (const float*)d_in[6];
    float* y = (float*)d_out;

    const int n_out = in_sizes[1] - 1;
    const int grid  = (n_out + NT - 1) / NT;

    const size_t n_x  = (size_t)in_sizes[0];
    const size_t n_w  = (size_t)in_sizes[4];
    const size_t xb_bytes = n_x * sizeof(unsigned short);
    const size_t need = xb_bytes + n_w * sizeof(unsigned short);

    if (ws_size >= need) {
        unsigned short* xb = (unsigned short*)d_ws;
        unsigned short* wb = (unsigned short*)((char*)d_ws + xb_bytes);
        hipLaunchKernelGGL(convert_all, dim3(2048), dim3(256), 0, stream,
                           x, W, (unsigned int*)xb, (unsigned int*)wb,
                           (long)(n_x >> 2), (long)(n_w >> 2));
        hipLaunchKernelGGL(sage_nobar, dim3(grid), dim3(NTHREADS), 0, stream,
                           xb, wb, rp, ci, lb, bb, y, n_out);
    } else {
        hipLaunchKernelGGL(sage_fused3, dim3(grid), dim3(NTHREADS), 0, stream,
                           x, rp, ci, W, lb, bb, y, n_out);
    }
}

// Round 6
// 87.444 us; speedup vs baseline: 1.5231x; 1.5231x over previous
//
#include <hip/hip_runtime.h>
#include <hip/hip_bf16.h>

#define D 128          // D_IN == D_OUT
#define K2 256         // 2*D (concat width)
#define NT 64          // nodes per block (16 per wave)
#define NTHREADS 256
#define AGG_LD 264     // bf16 elems per aggB row -> 528B stride (bank-spread A-frag reads)
#define WT_LD 40       // bf16 elems per wtT row -> 80B stride (bank-spread B-frag reads)

typedef __attribute__((ext_vector_type(8))) short bf16x8;  // MFMA A/B frag
typedef __attribute__((ext_vector_type(4))) float f32x4;   // MFMA C/D frag
typedef __attribute__((ext_vector_type(2))) float f32x2;

static __device__ __forceinline__ unsigned short f2bf(float f) {
    __hip_bfloat16 h = __float2bfloat16(f);   // RNE
    return *reinterpret_cast<unsigned short*>(&h);
}

// ---------------- fp8 e4m3 (OCP) encode/decode helpers ----------------
static __device__ __forceinline__ unsigned int f2q_manual(float f) {
    // clamp to e4m3 range, scale into fp8-aligned exponent window, RNE on bit 20
    f = fminf(fmaxf(f, -448.f), 448.f);
    unsigned int u = __float_as_uint(f * 0x1.0p-120f);
    const unsigned int lsb = (u >> 20) & 1u;
    u += 0x7ffffu + lsb;
    return ((u >> 24) & 0x80u) | ((u >> 20) & 0x7fu);
}
static __device__ __forceinline__ float q2f_manual(unsigned int b) {
    const unsigned int bits = ((b & 0x80u) << 24) | ((b & 0x7fu) << 20);
    return __uint_as_float(bits) * 0x1.0p+120f;   // subnormals exact modulo FTZ (err<2^-6, harmless)
}
static __device__ __forceinline__ unsigned int pack_fp8x4(float4 v) {
#if __has_builtin(__builtin_amdgcn_cvt_pk_fp8_f32)
    int lo = __builtin_amdgcn_cvt_pk_fp8_f32(v.x, v.y, 0, false);
    int q  = __builtin_amdgcn_cvt_pk_fp8_f32(v.z, v.w, lo, true);
    return (unsigned int)q;
#else
    return f2q_manual(v.x) | (f2q_manual(v.y) << 8) |
           (f2q_manual(v.z) << 16) | (f2q_manual(v.w) << 24);
#endif
}
static __device__ __forceinline__ f32x2 unpack_fp8x2(unsigned short v) {
#if __has_builtin(__builtin_amdgcn_cvt_pk_f32_fp8)
    return __builtin_amdgcn_cvt_pk_f32_fp8((int)(unsigned int)v, false);
#else
    f32x2 r;
    r[0] = q2f_manual(v & 0xffu);
    r[1] = q2f_manual((v >> 8) & 0xffu);
    return r;
#endif
}

// ------ Kernel A: x -> fp8 table (all rows) + bf16 self rows + bf16 W ------
__global__ __launch_bounds__(256)
void convert_all(const float* __restrict__ x, const float* __restrict__ W,
                 unsigned int* __restrict__ xq4,   // 4 fp8 per uint
                 uint2* __restrict__ xbs4,         // 4 bf16 per uint2 (self rows)
                 uint2* __restrict__ wb4,          // 4 bf16 per uint2
                 long n4x, long n4s, long n4w)
{
    const long gid = (long)blockIdx.x * blockDim.x + threadIdx.x;
    const long stride = (long)gridDim.x * blockDim.x;
    for (long t = gid; t < n4x; t += stride) {
        const float4 v = reinterpret_cast<const float4*>(x)[t];
        xq4[t] = pack_fp8x4(v);
        if (t < n4s) {
            uint2 p;
            p.x = (unsigned int)f2bf(v.x) | ((unsigned int)f2bf(v.y) << 16);
            p.y = (unsigned int)f2bf(v.z) | ((unsigned int)f2bf(v.w) << 16);
            xbs4[t] = p;
        }
    }
    for (long t = gid; t < n4w; t += stride) {
        const float4 v = reinterpret_cast<const float4*>(W)[t];
        uint2 p;
        p.x = (unsigned int)f2bf(v.x) | ((unsigned int)f2bf(v.y) << 16);
        p.y = (unsigned int)f2bf(v.z) | ((unsigned int)f2bf(v.w) << 16);
        wb4[t] = p;
    }
}

// ---- Kernel B: fp8 gather + mean, bf16 self/concat, MFMA GEMM (R4 structure) ----
__global__ __launch_bounds__(NTHREADS, 3)
void sage_fp8(const unsigned char* __restrict__ xq,
              const unsigned short* __restrict__ xbs,
              const unsigned short* __restrict__ wb,
              const int* __restrict__ rp,
              const int* __restrict__ ci,
              const float* __restrict__ lb,
              const float* __restrict__ bb,
              float* __restrict__ y,
              int n_out)
{
    __shared__ unsigned short aggB[NT][AGG_LD];  // bf16 [self(128) | mean(128)]
    __shared__ unsigned short wtT[D][WT_LD];     // bf16 wtT[o][kk] = W[o][k0+kk]
    __shared__ int rpls[NT + 1];
    __shared__ int cils[NT * 16];

    const int tid   = threadIdx.x;
    const int wave  = tid >> 6;
    const int lane  = tid & 63;
    const int node0 = blockIdx.x * NT;
    const int nt_act = min(NT, n_out - node0);

    if (tid <= nt_act) rpls[tid] = rp[node0 + tid];
    __syncthreads();
    const int e_base = rpls[0];
    const int e_cnt  = rpls[nt_act] - e_base;
    const bool fits  = (e_cnt <= NT * 16);
    if (fits) {
        for (int i = tid; i < e_cnt; i += NTHREADS) cils[i] = ci[e_base + i];
    }
    __syncthreads();

    // ---- Phase 1: gather (fp8 rows, 2 nodes/iter -> 32 independent 2B/lane loads) ----
    for (int t = 0; t < 16; t += 2) {
        const int nn0 = wave * 16 + t;
        if (nn0 >= nt_act) break;
        const int nn1 = nn0 + 1;
        const bool has1 = (nn1 < nt_act);

        const int s0 = rpls[nn0] - e_base;
        const int d0 = rpls[nn0 + 1] - e_base - s0;
        const int s1 = has1 ? rpls[nn1] - e_base : 0;
        const int d1 = has1 ? rpls[nn1 + 1] - e_base - s1 : 0;

        // self rows from bf16 self table (lane covers dims 2l, 2l+1)
        const unsigned int self0 = *reinterpret_cast<const unsigned int*>(
            &xbs[(size_t)(node0 + nn0) * D + lane * 2]);
        unsigned int self1 = 0;
        if (has1) self1 = *reinterpret_cast<const unsigned int*>(
            &xbs[(size_t)(node0 + nn1) * D + lane * 2]);

        float a0x = 0.f, a0y = 0.f, a1x = 0.f, a1y = 0.f;
        if (fits && has1 && d0 == 16 && d1 == 16) {
            int idx0[16], idx1[16];
            #pragma unroll
            for (int u = 0; u < 16; ++u) { idx0[u] = cils[s0 + u]; idx1[u] = cils[s1 + u]; }
            #pragma unroll
            for (int u = 0; u < 16; ++u) {
                const unsigned short v0 = *reinterpret_cast<const unsigned short*>(
                    &xq[(size_t)idx0[u] * D + lane * 2]);
                const unsigned short v1 = *reinterpret_cast<const unsigned short*>(
                    &xq[(size_t)idx1[u] * D + lane * 2]);
                const f32x2 e0 = unpack_fp8x2(v0);
                const f32x2 e1 = unpack_fp8x2(v1);
                a0x += e0[0]; a0y += e0[1];
                a1x += e1[0]; a1y += e1[1];
            }
        } else {
            for (int u = 0; u < d0; ++u) {
                const int c = fits ? cils[s0 + u] : ci[e_base + s0 + u];
                const f32x2 e0 = unpack_fp8x2(*reinterpret_cast<const unsigned short*>(
                    &xq[(size_t)c * D + lane * 2]));
                a0x += e0[0]; a0y += e0[1];
            }
            for (int u = 0; u < d1; ++u) {
                const int c = fits ? cils[s1 + u] : ci[e_base + s1 + u];
                const f32x2 e1 = unpack_fp8x2(*reinterpret_cast<const unsigned short*>(
                    &xq[(size_t)c * D + lane * 2]));
                a1x += e1[0]; a1y += e1[1];
            }
        }

        const float inv0 = 1.0f / (float)max(d0, 1);
        *reinterpret_cast<unsigned int*>(&aggB[nn0][lane * 2]) = self0;
        *reinterpret_cast<unsigned int*>(&aggB[nn0][D + lane * 2]) =
            (unsigned int)f2bf(a0x * inv0) | ((unsigned int)f2bf(a0y * inv0) << 16);
        if (has1) {
            const float inv1 = 1.0f / (float)max(d1, 1);
            *reinterpret_cast<unsigned int*>(&aggB[nn1][lane * 2]) = self1;
            *reinterpret_cast<unsigned int*>(&aggB[nn1][D + lane * 2]) =
                (unsigned int)f2bf(a1x * inv1) | ((unsigned int)f2bf(a1y * inv1) << 16);
        }
    }
    // (first __syncthreads in GEMM loop publishes aggB)

    // ---- Phase 2: MFMA GEMM. Per wave: M=16 nodes x N=128 outs, K=256 ----
    const int n15 = lane & 15;
    const int g   = lane >> 4;

    f32x4 acc[8];
    #pragma unroll
    for (int f = 0; f < 8; ++f) acc[f] = (f32x4){0.f, 0.f, 0.f, 0.f};

    for (int k0 = 0; k0 < K2; k0 += 32) {
        // Stage wtT[o][kk] = wb[o][k0+kk] (bf16 copy, uint4 per thread x2)
        #pragma unroll
        for (int j = 0; j < 2; ++j) {
            const int idx = j * 256 + tid;       // 512 x 16B
            const int o   = idx >> 2;            // 0..127
            const int q   = idx & 3;             // 0..3
            *reinterpret_cast<uint4*>(&wtT[o][q * 8]) =
                *reinterpret_cast<const uint4*>(&wb[(size_t)o * K2 + k0 + q * 8]);
        }
        __syncthreads();

        const bf16x8 a = *reinterpret_cast<const bf16x8*>(
            &aggB[wave * 16 + n15][k0 + g * 8]);
        #pragma unroll
        for (int f = 0; f < 8; ++f) {
            const bf16x8 b = *reinterpret_cast<const bf16x8*>(&wtT[f * 16 + n15][g * 8]);
            acc[f] = __builtin_amdgcn_mfma_f32_16x16x32_bf16(a, b, acc[f], 0, 0, 0);
        }
        __syncthreads();
    }

    // ---- Epilogue: D layout col = lane&15, row = (lane>>4)*4 + reg ----
    const int mbase = node0 + wave * 16 + g * 4;
    #pragma unroll
    for (int f = 0; f < 8; ++f) {
        const int col  = f * 16 + n15;
        const float bs = lb[col] + bb[col];
        #pragma unroll
        for (int r = 0; r < 4; ++r) {
            const int row = mbase + r;
            if (row < n_out)
                y[(size_t)row * D + col] = acc[f][r] + bs;
        }
    }
}

// --------- Fallback (fp32 gather, barriered) if ws too small ---------
__global__ __launch_bounds__(NTHREADS, 3)
void sage_fused3(const float* __restrict__ x,
                 const int* __restrict__ rp,
                 const int* __restrict__ ci,
                 const float* __restrict__ W,
                 const float* __restrict__ lb,
                 const float* __restrict__ bb,
                 float* __restrict__ y,
                 int n_out)
{
    __shared__ unsigned short aggB[NT][AGG_LD];
    __shared__ unsigned short wtT[D][32];
    __shared__ int rpls[NT + 1];
    __shared__ int cilsF[NT * 16];

    const int tid   = threadIdx.x;
    const int wave  = tid >> 6;
    const int lane  = tid & 63;
    const int node0 = blockIdx.x * NT;
    const int nt_act = min(NT, n_out - node0);

    if (tid <= nt_act) rpls[tid] = rp[node0 + tid];
    __syncthreads();
    const int e_base = rpls[0];
    const int e_cnt  = rpls[nt_act] - e_base;
    const bool fits  = (e_cnt <= NT * 16);
    if (fits) {
        for (int i = tid; i < e_cnt; i += NTHREADS) cilsF[i] = ci[e_base + i];
    }
    __syncthreads();

    for (int t = 0; t < 16; ++t) {
        const int nn = wave * 16 + t;
        if (nn >= nt_act) break;
        const int node = node0 + nn;
        const float2 self =
            *reinterpret_cast<const float2*>(&x[(size_t)node * D + lane * 2]);
        const int s  = rpls[nn] - e_base;
        const int dg = rpls[nn + 1] - e_base - s;
        float ax = 0.f, ay = 0.f;
        for (int u = 0; u < dg; ++u) {
            const int c = fits ? cilsF[s + u] : ci[e_base + s + u];
            const float2 v = *reinterpret_cast<const float2*>(
                &x[(size_t)c * D + lane * 2]);
            ax += v.x; ay += v.y;
        }
        const float inv = 1.0f / (float)max(dg, 1);
        *reinterpret_cast<unsigned int*>(&aggB[nn][lane * 2]) =
            (unsigned int)f2bf(self.x) | ((unsigned int)f2bf(self.y) << 16);
        *reinterpret_cast<unsigned int*>(&aggB[nn][D + lane * 2]) =
            (unsigned int)f2bf(ax * inv) | ((unsigned int)f2bf(ay * inv) << 16);
    }

    const int n15 = lane & 15;
    const int g   = lane >> 4;
    f32x4 acc[8];
    #pragma unroll
    for (int f = 0; f < 8; ++f) acc[f] = (f32x4){0.f, 0.f, 0.f, 0.f};

    for (int k0 = 0; k0 < K2; k0 += 32) {
        #pragma unroll
        for (int j = 0; j < 4; ++j) {
            const int idx = j * 256 + tid;
            const int o   = idx >> 3;
            const int c   = idx & 7;
            const float4 w = *reinterpret_cast<const float4*>(
                &W[(size_t)o * K2 + k0 + c * 4]);
            const unsigned int lo = (unsigned int)f2bf(w.x) | ((unsigned int)f2bf(w.y) << 16);
            const unsigned int hi = (unsigned int)f2bf(w.z) | ((unsigned int)f2bf(w.w) << 16);
            *reinterpret_cast<uint2*>(&wtT[o][c * 4]) = make_uint2(lo, hi);
        }
        __syncthreads();
        const bf16x8 a = *reinterpret_cast<const bf16x8*>(
            &aggB[wave * 16 + n15][k0 + g * 8]);
        #pragma unroll
        for (int f = 0; f < 8; ++f) {
            const bf16x8 b = *reinterpret_cast<const bf16x8*>(&wtT[f * 16 + n15][g * 8]);
            acc[f] = __builtin_amdgcn_mfma_f32_16x16x32_bf16(a, b, acc[f], 0, 0, 0);
        }
        __syncthreads();
    }

    const int mbase = node0 + wave * 16 + g * 4;
    #pragma unroll
    for (int f = 0; f < 8; ++f) {
        const int col  = f * 16 + n15;
        const float bs = lb[col] + bb[col];
        #pragma unroll
        for (int r = 0; r < 4; ++r) {
            const int row = mbase + r;
            if (row < n_out)
                y[(size_t)row * D + col] = acc[f][r] + bs;
        }
    }
}

extern "C" void kernel_launch(void* const* d_in, const int* in_sizes, int n_in,
                              void* d_out, int out_size, void* d_ws, size_t ws_size,
                              hipStream_t stream)
{
    const float* x  = (const float*)d_in[0];
    const int*   rp = (const int*)d_in[1];
    const int*   ci = (const int*)d_in[2];
    // d_in[3] = sample_count (scalar) — degree comes from row_ptr
    const float* W  = (const float*)d_in[4];
    const float* lb = (const float*)d_in[5];
    const float* bb = (const float*)d_in[6];
    float* y = (float*)d_out;

    const int n_out = in_sizes[1] - 1;
    const int grid  = (n_out + NT - 1) / NT;

    const size_t n_x = (size_t)in_sizes[0];
    const size_t n_w = (size_t)in_sizes[4];
    const size_t xq_bytes  = n_x;                         // fp8: 1 B/elem
    const size_t xbs_bytes = (size_t)n_out * D * 2;       // bf16 self rows
    const size_t wb_bytes  = n_w * 2;
    const size_t need = xq_bytes + xbs_bytes + wb_bytes;

    if (ws_size >= need) {
        unsigned char*  xq  = (unsigned char*)d_ws;
        unsigned short* xbs = (unsigned short*)((char*)d_ws + xq_bytes);
        unsigned short* wb  = (unsigned short*)((char*)d_ws + xq_bytes + xbs_bytes);
        hipLaunchKernelGGL(convert_all, dim3(2048), dim3(256), 0, stream,
                           x, W, (unsigned int*)xq, (uint2*)xbs, (uint2*)wb,
                           (long)(n_x >> 2), (long)(((size_t)n_out * D) >> 2),
                           (long)(n_w >> 2));
        hipLaunchKernelGGL(sage_fp8, dim3(grid), dim3(NTHREADS), 0, stream,
                           xq, xbs, wb, rp, ci, lb, bb, y, n_out);
    } else {
        hipLaunchKernelGGL(sage_fused3, dim3(grid), dim3(NTHREADS), 0, stream,
                           x, rp, ci, W, lb, bb, y, n_out);
    }
}

// Round 7
// 78.933 us; speedup vs baseline: 1.6873x; 1.1078x over previous
//
#include <hip/hip_runtime.h>
#include <hip/hip_bf16.h>

#define D 128          // D_IN == D_OUT
#define K2 256         // 2*D (concat width)
#define NT 64          // nodes per block (16 per wave)
#define NTHREADS 256
#define AGM_LD 136     // aggM row stride (bf16) -> 272B: bank-clean b64/b128
#define WT_LD 68       // wtT row stride (bf16) -> 136B: bank-clean b64/b128

typedef __attribute__((ext_vector_type(8))) short bf16x8;  // MFMA A/B frag
typedef __attribute__((ext_vector_type(4))) float f32x4;   // MFMA C/D frag
typedef __attribute__((ext_vector_type(2))) float f32x2;

static __device__ __forceinline__ unsigned short f2bf(float f) {
    __hip_bfloat16 h = __float2bfloat16(f);   // RNE
    return *reinterpret_cast<unsigned short*>(&h);
}

// ---------------- fp8 e4m3 (OCP) encode/decode helpers ----------------
static __device__ __forceinline__ unsigned int f2q_manual(float f) {
    f = fminf(fmaxf(f, -448.f), 448.f);
    unsigned int u = __float_as_uint(f * 0x1.0p-120f);
    const unsigned int lsb = (u >> 20) & 1u;
    u += 0x7ffffu + lsb;
    return ((u >> 24) & 0x80u) | ((u >> 20) & 0x7fu);
}
static __device__ __forceinline__ float q2f_manual(unsigned int b) {
    const unsigned int bits = ((b & 0x80u) << 24) | ((b & 0x7fu) << 20);
    return __uint_as_float(bits) * 0x1.0p+120f;
}
static __device__ __forceinline__ unsigned int pack_fp8x4(float4 v) {
#if __has_builtin(__builtin_amdgcn_cvt_pk_fp8_f32)
    int lo = __builtin_amdgcn_cvt_pk_fp8_f32(v.x, v.y, 0, false);
    int q  = __builtin_amdgcn_cvt_pk_fp8_f32(v.z, v.w, lo, true);
    return (unsigned int)q;
#else
    return f2q_manual(v.x) | (f2q_manual(v.y) << 8) |
           (f2q_manual(v.z) << 16) | (f2q_manual(v.w) << 24);
#endif
}
static __device__ __forceinline__ f32x2 unpack_fp8_lo(unsigned int v) {
#if __has_builtin(__builtin_amdgcn_cvt_pk_f32_fp8)
    return __builtin_amdgcn_cvt_pk_f32_fp8((int)v, false);
#else
    f32x2 r; r[0] = q2f_manual(v & 0xffu); r[1] = q2f_manual((v >> 8) & 0xffu); return r;
#endif
}
static __device__ __forceinline__ f32x2 unpack_fp8_hi(unsigned int v) {
#if __has_builtin(__builtin_amdgcn_cvt_pk_f32_fp8)
    return __builtin_amdgcn_cvt_pk_f32_fp8((int)v, true);
#else
    f32x2 r; r[0] = q2f_manual((v >> 16) & 0xffu); r[1] = q2f_manual((v >> 24) & 0xffu); return r;
#endif
}

// ------ Kernel A: x -> fp8 table (all rows) + bf16 self rows + bf16 W ------
__global__ __launch_bounds__(256)
void convert_all(const float* __restrict__ x, const float* __restrict__ W,
                 unsigned int* __restrict__ xq4,   // 4 fp8 per uint
                 uint2* __restrict__ xbs4,         // 4 bf16 per uint2 (self rows)
                 uint2* __restrict__ wb4,          // 4 bf16 per uint2
                 long n4x, long n4s, long n4w)
{
    const long gid = (long)blockIdx.x * blockDim.x + threadIdx.x;
    const long stride = (long)gridDim.x * blockDim.x;
    for (long t = gid; t < n4x; t += stride) {
        const float4 v = reinterpret_cast<const float4*>(x)[t];
        xq4[t] = pack_fp8x4(v);
        if (t < n4s) {
            uint2 p;
            p.x = (unsigned int)f2bf(v.x) | ((unsigned int)f2bf(v.y) << 16);
            p.y = (unsigned int)f2bf(v.z) | ((unsigned int)f2bf(v.w) << 16);
            xbs4[t] = p;
        }
    }
    for (long t = gid; t < n4w; t += stride) {
        const float4 v = reinterpret_cast<const float4*>(W)[t];
        uint2 p;
        p.x = (unsigned int)f2bf(v.x) | ((unsigned int)f2bf(v.y) << 16);
        p.y = (unsigned int)f2bf(v.z) | ((unsigned int)f2bf(v.w) << 16);
        wb4[t] = p;
    }
}

// ---- Kernel B: fp8 gather (4B/lane, node-split wave) + mean + MFMA GEMM ----
__global__ __launch_bounds__(NTHREADS, 4)
void sage_fp8b(const unsigned char* __restrict__ xq,
               const unsigned short* __restrict__ xbs,
               const unsigned short* __restrict__ wb,
               const int* __restrict__ rp,
               const int* __restrict__ ci,
               const float* __restrict__ lb,
               const float* __restrict__ bb,
               float* __restrict__ y,
               int n_out)
{
    __shared__ unsigned short aggM[NT][AGM_LD];  // bf16 mean half only
    __shared__ unsigned short wtT[D][WT_LD];     // bf16 W chunk: wtT[o][k-k0]
    __shared__ int rpls[NT + 1];
    __shared__ int cils[NT * 16];

    const int tid   = threadIdx.x;
    const int wave  = tid >> 6;
    const int lane  = tid & 63;
    const int node0 = blockIdx.x * NT;
    const int nt_act = min(NT, n_out - node0);

    if (tid <= nt_act) rpls[tid] = rp[node0 + tid];
    __syncthreads();
    const int e_base = rpls[0];
    const int e_cnt  = rpls[nt_act] - e_base;
    const bool fits  = (e_cnt <= NT * 16);
    if (fits) {
        for (int i = tid; i < e_cnt; i += NTHREADS) cils[i] = ci[e_base + i];
    }
    __syncthreads();

    // ---- Phase 1: gather. Lane split: nsel = lane>>5 picks node of the pair;
    //      each lane owns 4 dims (4 fp8 bytes) -> 16 loads/lane per pair. ----
    const int nsel = lane >> 5;
    const int dg4  = (lane & 31) * 4;            // dim base (0,4,...,124)

    for (int p = 0; p < 8; ++p) {
        const int n0 = wave * 16 + p * 2;
        if (n0 >= nt_act) break;
        const bool has1 = (n0 + 1 < nt_act);

        const int s0 = rpls[n0] - e_base;
        const int d0 = rpls[n0 + 1] - e_base - s0;
        int s1 = s0, d1 = d0;
        if (has1) { s1 = rpls[n0 + 1] - e_base; d1 = rpls[n0 + 2] - e_base - s1; }

        const int  my_n   = n0 + nsel;
        const int  my_s   = nsel ? s1 : s0;
        const int  my_d   = nsel ? d1 : d0;
        const bool active = (nsel == 0) || has1;

        float a0 = 0.f, a1 = 0.f, a2 = 0.f, a3 = 0.f;
        if (fits && has1 && d0 == 16 && d1 == 16) {
            int idx[16];
            #pragma unroll
            for (int u = 0; u < 16; ++u) idx[u] = cils[my_s + u];
            #pragma unroll
            for (int u = 0; u < 16; ++u) {
                const unsigned int v = *reinterpret_cast<const unsigned int*>(
                    &xq[(size_t)idx[u] * D + dg4]);
                const f32x2 lo = unpack_fp8_lo(v);
                const f32x2 hi = unpack_fp8_hi(v);
                a0 += lo[0]; a1 += lo[1]; a2 += hi[0]; a3 += hi[1];
            }
        } else if (active) {
            for (int u = 0; u < my_d; ++u) {
                const int c = fits ? cils[my_s + u] : ci[e_base + my_s + u];
                const unsigned int v = *reinterpret_cast<const unsigned int*>(
                    &xq[(size_t)c * D + dg4]);
                const f32x2 lo = unpack_fp8_lo(v);
                const f32x2 hi = unpack_fp8_hi(v);
                a0 += lo[0]; a1 += lo[1]; a2 += hi[0]; a3 += hi[1];
            }
        }
        if (active) {
            const float inv = 1.0f / (float)max(my_d, 1);
            uint2 pk;
            pk.x = (unsigned int)f2bf(a0 * inv) | ((unsigned int)f2bf(a1 * inv) << 16);
            pk.y = (unsigned int)f2bf(a2 * inv) | ((unsigned int)f2bf(a3 * inv) << 16);
            *reinterpret_cast<uint2*>(&aggM[my_n][dg4]) = pk;   // 8B, bank-clean
        }
    }
    // (first __syncthreads in GEMM loop publishes aggM)

    // ---- Phase 2: MFMA GEMM. Per wave: M=16 x N=128, K=256 in 4 chunks ----
    const int n15 = lane & 15;
    const int g   = lane >> 4;

    // Hoist the 4 self A-frags (k=0..127) from global bf16 self table:
    // lane(n15,g) reads 16B at row (node) n15, k = c*32 + g*8 — 64B/row segments.
    const int arow = min(node0 + wave * 16 + n15, n_out - 1);
    bf16x8 aself[4];
    #pragma unroll
    for (int c = 0; c < 4; ++c)
        aself[c] = *reinterpret_cast<const bf16x8*>(
            &xbs[(size_t)arow * D + c * 32 + g * 8]);

    f32x4 acc[8];
    #pragma unroll
    for (int f = 0; f < 8; ++f) acc[f] = (f32x4){0.f, 0.f, 0.f, 0.f};

    #pragma unroll
    for (int ch = 0; ch < 4; ++ch) {             // k0 = ch*64
        const int k0 = ch * 64;
        // Stage wtT[o][0..63] = wb[o][k0..k0+63]; uint2 per thread x8.
        #pragma unroll
        for (int j = 0; j < 8; ++j) {
            const int flat = j * 256 + tid;      // 2048 uint2
            const int o    = flat >> 4;          // 0..127
            const int q    = flat & 15;          // 0..15
            *reinterpret_cast<uint2*>(&wtT[o][q * 4]) =
                *reinterpret_cast<const uint2*>(&wb[(size_t)o * K2 + k0 + q * 4]);
        }
        __syncthreads();

        #pragma unroll
        for (int sub = 0; sub < 2; ++sub) {      // kk = k0 + sub*32
            const int kk = k0 + sub * 32;
            const bf16x8 a = (kk < 128)
                ? aself[ch * 2 + sub]
                : *reinterpret_cast<const bf16x8*>(
                      &aggM[wave * 16 + n15][(kk - 128) + g * 8]);
            #pragma unroll
            for (int f = 0; f < 8; ++f) {
                const bf16x8 b = *reinterpret_cast<const bf16x8*>(
                    &wtT[f * 16 + n15][sub * 32 + g * 8]);
                acc[f] = __builtin_amdgcn_mfma_f32_16x16x32_bf16(a, b, acc[f], 0, 0, 0);
            }
        }
        __syncthreads();
    }

    // ---- Epilogue: D layout col = lane&15, row = (lane>>4)*4 + reg ----
    const int mbase = node0 + wave * 16 + g * 4;
    #pragma unroll
    for (int f = 0; f < 8; ++f) {
        const int col  = f * 16 + n15;
        const float bs = lb[col] + bb[col];
        #pragma unroll
        for (int r = 0; r < 4; ++r) {
            const int row = mbase + r;
            if (row < n_out)
                y[(size_t)row * D + col] = acc[f][r] + bs;
        }
    }
}

// --------- Fallback (fp32 gather, barriered) if ws too small ---------
#define AGG_LDF 264
__global__ __launch_bounds__(NTHREADS, 3)
void sage_fused3(const float* __restrict__ x,
                 const int* __restrict__ rp,
                 const int* __restrict__ ci,
                 const float* __restrict__ W,
                 const float* __restrict__ lb,
                 const float* __restrict__ bb,
                 float* __restrict__ y,
                 int n_out)
{
    __shared__ unsigned short aggB[NT][AGG_LDF];
    __shared__ unsigned short wtTF[D][32];
    __shared__ int rpls[NT + 1];
    __shared__ int cilsF[NT * 16];

    const int tid   = threadIdx.x;
    const int wave  = tid >> 6;
    const int lane  = tid & 63;
    const int node0 = blockIdx.x * NT;
    const int nt_act = min(NT, n_out - node0);

    if (tid <= nt_act) rpls[tid] = rp[node0 + tid];
    __syncthreads();
    const int e_base = rpls[0];
    const int e_cnt  = rpls[nt_act] - e_base;
    const bool fits  = (e_cnt <= NT * 16);
    if (fits) {
        for (int i = tid; i < e_cnt; i += NTHREADS) cilsF[i] = ci[e_base + i];
    }
    __syncthreads();

    for (int t = 0; t < 16; ++t) {
        const int nn = wave * 16 + t;
        if (nn >= nt_act) break;
        const int node = node0 + nn;
        const float2 self =
            *reinterpret_cast<const float2*>(&x[(size_t)node * D + lane * 2]);
        const int s  = rpls[nn] - e_base;
        const int dg = rpls[nn + 1] - e_base - s;
        float ax = 0.f, ay = 0.f;
        for (int u = 0; u < dg; ++u) {
            const int c = fits ? cilsF[s + u] : ci[e_base + s + u];
            const float2 v = *reinterpret_cast<const float2*>(
                &x[(size_t)c * D + lane * 2]);
            ax += v.x; ay += v.y;
        }
        const float inv = 1.0f / (float)max(dg, 1);
        *reinterpret_cast<unsigned int*>(&aggB[nn][lane * 2]) =
            (unsigned int)f2bf(self.x) | ((unsigned int)f2bf(self.y) << 16);
        *reinterpret_cast<unsigned int*>(&aggB[nn][D + lane * 2]) =
            (unsigned int)f2bf(ax * inv) | ((unsigned int)f2bf(ay * inv) << 16);
    }

    const int n15 = lane & 15;
    const int g   = lane >> 4;
    f32x4 acc[8];
    #pragma unroll
    for (int f = 0; f < 8; ++f) acc[f] = (f32x4){0.f, 0.f, 0.f, 0.f};

    for (int k0 = 0; k0 < K2; k0 += 32) {
        #pragma unroll
        for (int j = 0; j < 4; ++j) {
            const int idx = j * 256 + tid;
            const int o   = idx >> 3;
            const int c   = idx & 7;
            const float4 w = *reinterpret_cast<const float4*>(
                &W[(size_t)o * K2 + k0 + c * 4]);
            const unsigned int lo = (unsigned int)f2bf(w.x) | ((unsigned int)f2bf(w.y) << 16);
            const unsigned int hi = (unsigned int)f2bf(w.z) | ((unsigned int)f2bf(w.w) << 16);
            *reinterpret_cast<uint2*>(&wtTF[o][c * 4]) = make_uint2(lo, hi);
        }
        __syncthreads();
        const bf16x8 a = *reinterpret_cast<const bf16x8*>(
            &aggB[wave * 16 + n15][k0 + g * 8]);
        #pragma unroll
        for (int f = 0; f < 8; ++f) {
            const bf16x8 b = *reinterpret_cast<const bf16x8*>(&wtTF[f * 16 + n15][g * 8]);
            acc[f] = __builtin_amdgcn_mfma_f32_16x16x32_bf16(a, b, acc[f], 0, 0, 0);
        }
        __syncthreads();
    }

    const int mbase = node0 + wave * 16 + g * 4;
    #pragma unroll
    for (int f = 0; f < 8; ++f) {
        const int col  = f * 16 + n15;
        const float bs = lb[col] + bb[col];
        #pragma unroll
        for (int r = 0; r < 4; ++r) {
            const int row = mbase + r;
            if (row < n_out)
                y[(size_t)row * D + col] = acc[f][r] + bs;
        }
    }
}

extern "C" void kernel_launch(void* const* d_in, const int* in_sizes, int n_in,
                              void* d_out, int out_size, void* d_ws, size_t ws_size,
                              hipStream_t stream)
{
    const float* x  = (const float*)d_in[0];
    const int*   rp = (const int*)d_in[1];
    const int*   ci = (const int*)d_in[2];
    // d_in[3] = sample_count (scalar) — degree comes from row_ptr
    const float* W  = (const float*)d_in[4];
    const float* lb = (const float*)d_in[5];
    const float* bb = (const float*)d_in[6];
    float* y = (float*)d_out;

    const int n_out = in_sizes[1] - 1;
    const int grid  = (n_out + NT - 1) / NT;

    const size_t n_x = (size_t)in_sizes[0];
    const size_t n_w = (size_t)in_sizes[4];
    const size_t xq_bytes  = n_x;                         // fp8: 1 B/elem
    const size_t xbs_bytes = (size_t)n_out * D * 2;       // bf16 self rows
    const size_t wb_bytes  = n_w * 2;
    const size_t need = xq_bytes + xbs_bytes + wb_bytes;

    if (ws_size >= need) {
        unsigned char*  xq  = (unsigned char*)d_ws;
        unsigned short* xbs = (unsigned short*)((char*)d_ws + xq_bytes);
        unsigned short* wb  = (unsigned short*)((char*)d_ws + xq_bytes + xbs_bytes);
        hipLaunchKernelGGL(convert_all, dim3(2048), dim3(256), 0, stream,
                           x, W, (unsigned int*)xq, (uint2*)xbs, (uint2*)wb,
                           (long)(n_x >> 2), (long)(((size_t)n_out * D) >> 2),
                           (long)(n_w >> 2));
        hipLaunchKernelGGL(sage_fp8b, dim3(grid), dim3(NTHREADS), 0, stream,
                           xq, xbs, wb, rp, ci, lb, bb, y, n_out);
    } else {
        hipLaunchKernelGGL(sage_fused3, dim3(grid), dim3(NTHREADS), 0, stream,
                           x, rp, ci, W, lb, bb, y, n_out);
    }
}